// Round 11
// baseline (209.537 us; speedup 1.0000x reference)
//
#include <hip/hip_runtime.h>

#define N_NODES 100000
#define D 64
#define BIN_ROWS 64
#define NBINS 1563          // ceil(100000 / 64)
#define PE 2048             // edges per hist/partition block
#define XWB 3125            // xw blocks (100000 / 32)

typedef unsigned int u32;

__device__ __forceinline__ float bf16_to_f32(unsigned short u) {
    union { u32 i; float f; } c; c.i = ((u32)u) << 16; return c.f;
}
__device__ __forceinline__ unsigned short f32_to_bf16(float f) {
    union { float f; u32 i; } c; c.f = f;
    const u32 u = c.i;
    return (unsigned short)((u + 0x7FFFu + ((u >> 16) & 1u)) >> 16);
}

// ---------------- K1: fused  y = bf16(x @ W^T)  (blocks < XWB)
// ----------------            per-block bin histogram (blocks >= XWB) ----------------
__global__ __launch_bounds__(256) void xw_hist_kernel(const float* __restrict__ x,
                                                      const float* __restrict__ W,
                                                      unsigned short* __restrict__ y,
                                                      const int* __restrict__ erow,
                                                      int* __restrict__ hist2d,
                                                      int* __restrict__ counter, int ne) {
    __shared__ union {
        struct { float Ws[D * 68]; float xs[32][D]; } g;
        int h[NBINS];
    } sm;
    const int tid = threadIdx.x;

    if (blockIdx.x == 0 && tid == 0) counter[0] = 0;     // scan fixup counter

    if (blockIdx.x >= XWB) {
        // ---- binhist: dense per-block histogram, no global atomics ----
        const int blk = blockIdx.x - XWB;
        for (int i = tid; i < NBINS; i += 256) sm.h[i] = 0;
        __syncthreads();
        const int base = blk * PE;
        const int end  = min(base + PE, ne);
        for (int e = base + tid; e < end; e += 256)
            atomicAdd(&sm.h[erow[e] >> 6], 1);           // LDS, no-return
        __syncthreads();
        for (int i = tid; i < NBINS; i += 256)
            hist2d[blk * NBINS + i] = sm.h[i];           // coalesced
        return;
    }

    // ---- xw: W register-resident, x via LDS broadcast ----
    for (int i = tid; i < D * D; i += 256)
        sm.g.Ws[(i >> 6) * 68 + (i & 63)] = W[i];

    const int nodeBase = blockIdx.x * 32;                // N_NODES = 3125*32 exactly
    for (int i = tid; i < 32 * D; i += 256)
        sm.g.xs[i >> 6][i & 63] = x[(nodeBase + (i >> 6)) * D + (i & 63)];
    __syncthreads();

    const int j = tid & 63, w = tid >> 6;
    float4 wr[16];
    const float4* WsRow = (const float4*)(sm.g.Ws + j * 68);
#pragma unroll
    for (int k = 0; k < 16; ++k) wr[k] = WsRow[k];

    for (int s = 0; s < 8; ++s) {
        const int local = w * 8 + s;
        const float4* xr = (const float4*)(&sm.g.xs[local][0]);
        float a0 = 0.f, a1 = 0.f, a2 = 0.f, a3 = 0.f;
#pragma unroll
        for (int k = 0; k < 16; k += 4) {
            const float4 x0 = xr[k], x1 = xr[k+1], x2 = xr[k+2], x3 = xr[k+3];
            a0 = fmaf(x0.x, wr[k].x, a0);   a0 = fmaf(x0.y, wr[k].y, a0);
            a0 = fmaf(x0.z, wr[k].z, a0);   a0 = fmaf(x0.w, wr[k].w, a0);
            a1 = fmaf(x1.x, wr[k+1].x, a1); a1 = fmaf(x1.y, wr[k+1].y, a1);
            a1 = fmaf(x1.z, wr[k+1].z, a1); a1 = fmaf(x1.w, wr[k+1].w, a1);
            a2 = fmaf(x2.x, wr[k+2].x, a2); a2 = fmaf(x2.y, wr[k+2].y, a2);
            a2 = fmaf(x2.z, wr[k+2].z, a2); a2 = fmaf(x2.w, wr[k+2].w, a2);
            a3 = fmaf(x3.x, wr[k+3].x, a3); a3 = fmaf(x3.y, wr[k+3].y, a3);
            a3 = fmaf(x3.z, wr[k+3].z, a3); a3 = fmaf(x3.w, wr[k+3].w, a3);
        }
        y[(nodeBase + local) * D + j] = f32_to_bf16((a0 + a1) + (a2 + a3));
    }
}

// ---------------- K2: scan (per-chunk exclusive, bin-major) + last-block bsum fixup ----------------
__global__ __launch_bounds__(256) void scan_kernel(const int* __restrict__ hist2d,
                                                   int* __restrict__ scan2d,
                                                   int* __restrict__ bsum,
                                                   int* __restrict__ counter,
                                                   int total, int npb, int nblocks) {
    __shared__ int sdat[256];
    __shared__ int flag;
    const int tid  = threadIdx.x;
    const int base = blockIdx.x * 1024 + tid * 4;
    int v[4], sum = 0;
    int bin = 0, blk = 0;
    if (base < total) { bin = base / npb; blk = base - bin * npb; }
#pragma unroll
    for (int k = 0; k < 4; ++k) {
        const int idx = base + k;
        v[k] = (idx < total) ? hist2d[blk * NBINS + bin] : 0;
        sum += v[k];
        if (++blk == npb) { blk = 0; ++bin; }
    }
    sdat[tid] = sum;
    __syncthreads();
    for (int d = 1; d < 256; d <<= 1) {
        const int t = (tid >= d) ? sdat[tid - d] : 0;
        __syncthreads();
        sdat[tid] += t;
        __syncthreads();
    }
    int run = sdat[tid] - sum;
#pragma unroll
    for (int k = 0; k < 4; ++k) {
        const int idx = base + k;
        if (idx < total) scan2d[idx] = run;
        run += v[k];
    }
    if (tid == 255) bsum[blockIdx.x] = sdat[255];

    // ---- last finishing block scans bsum in place ----
    __threadfence();
    if (tid == 0) flag = (atomicAdd(counter, 1) == nblocks - 1) ? 1 : 0;
    __syncthreads();
    if (!flag) return;
    __threadfence();
    int carry = 0;
    for (int b0 = 0; b0 < nblocks; b0 += 256) {
        const int i = b0 + tid;
        const int vv = (i < nblocks) ? bsum[i] : 0;
        __syncthreads();
        sdat[tid] = vv;
        __syncthreads();
        for (int d = 1; d < 256; d <<= 1) {
            const int t = (tid >= d) ? sdat[tid - d] : 0;
            __syncthreads();
            sdat[tid] += t;
            __syncthreads();
        }
        if (i < nblocks) bsum[i] = carry + sdat[tid] - vv;
        carry += sdat[255];
    }
}

// ---------------- K3: partition — precomputed cursors, single store pass ----------------
__global__ __launch_bounds__(256) void partition_kernel(const int* __restrict__ erow,
                                                        const int* __restrict__ ecol,
                                                        const float* __restrict__ eval_,
                                                        const int* __restrict__ scan2d,
                                                        const int* __restrict__ bsum,
                                                        u32* __restrict__ pedge,
                                                        int ne, int npb) {
    __shared__ int lcur[NBINS];
    const int blk = blockIdx.x;
    for (int i = threadIdx.x; i < NBINS; i += 256) {
        const int idx = i * npb + blk;
        lcur[i] = scan2d[idx] + bsum[idx >> 10];
    }
    __syncthreads();
    const int base = blk * PE;
    const int end  = min(base + PE, ne);
    for (int e = base + threadIdx.x; e < end; e += 256) {
        const int r   = erow[e];
        const int bin = r >> 6;
        const int pos = atomicAdd(&lcur[bin], 1);    // LDS-local rank
        int q = (int)(eval_[e] * 512.0f + 0.5f);
        q = (q > 511) ? 511 : q;
        pedge[pos] = ((u32)ecol[e] << 15) | ((u32)(r & 63) << 9) | (u32)q;
    }
}

// ---------------- K4: aggregate — ushort2 gathers, swizzled 16KB int LDS acc ----------------
// acc position for feature f: ((f&1)<<5) | (f>>1)  -> both ds_adds land on bank (lane&31)
__global__ __launch_bounds__(512) void aggregate_kernel(const int* __restrict__ scan2d,
                                                        const int* __restrict__ bsum,
                                                        const u32* __restrict__ pedge,
                                                        const u32* __restrict__ y2,
                                                        const float* __restrict__ b,
                                                        float4* __restrict__ out4,
                                                        int ne, int npb) {
    __shared__ int acc[BIN_ROWS * D];    // 16 KB
    const int tid = threadIdx.x;
    for (int i = tid; i < BIN_ROWS * D; i += 512) acc[i] = 0;
    __syncthreads();

    const int bin = blockIdx.x;
    const int hl  = tid & 31;            // u32 slot within row (features 2hl, 2hl+1)
    const int hi  = (tid >> 5) & 1;      // which edge of the pair
    const int w   = tid >> 6;            // 0..7
    const int i0  = bin * npb;
    const int s   = scan2d[i0] + bsum[i0 >> 10];
    int e;
    if (bin + 1 < NBINS) { const int i1 = (bin + 1) * npb; e = scan2d[i1] + bsum[i1 >> 10]; }
    else e = ne;

    for (int bb0 = s + w * 16; bb0 < e; bb0 += 128) {
        const int bb = __builtin_amdgcn_readfirstlane(bb0);
        u32 u[16];
        if (bb + 16 <= e) {
#pragma unroll
            for (int j = 0; j < 16; ++j) u[j] = pedge[bb + j];   // uniform -> s_load
        } else {
#pragma unroll
            for (int j = 0; j < 16; ++j) {
                const int idx = bb + j;
                u[j] = (idx < e) ? pedge[idx] : 0u;              // pad adds 0
            }
        }
        u32 ue[8], g2[8];
#pragma unroll
        for (int p = 0; p < 8; ++p) {                            // 8 gathers, 2 edges each
            ue[p] = hi ? u[2*p + 1] : u[2*p];
            g2[p] = y2[(ue[p] >> 15) * 32 + hl];                 // 4B/lane, 256B/inst
        }
#pragma unroll
        for (int p = 0; p < 8; ++p) {
            const float vq  = (float)(ue[p] & 511u);             // val * 512
            const int   r   = (int)((ue[p] >> 9) & 63u);
            const float ylo = bf16_to_f32((unsigned short)(g2[p] & 0xFFFFu));
            const float yhi = bf16_to_f32((unsigned short)(g2[p] >> 16));
            atomicAdd(&acc[r * 64 + hl],      (int)(vq * ylo * 512.0f));  // bank = hl
            atomicAdd(&acc[r * 64 + 32 + hl], (int)(vq * yhi * 512.0f));  // bank = hl
        }
    }
    __syncthreads();

    const int rowBase = bin * BIN_ROWS;
    const float INV = 1.0f / 262144.0f;
    for (int i = tid; i < BIN_ROWS * 16; i += 512) {
        const int rl = i >> 4, q = i & 15;
        const int row = rowBase + rl;
        if (row < N_NODES) {
            const float4 bv = ((const float4*)b)[q];
            const int* ar = &acc[rl * 64];
            float4 o;
            o.x = (float)ar[2*q]          * INV + bv.x;   // f=4q   -> pos 2q
            o.y = (float)ar[32 + 2*q]     * INV + bv.y;   // f=4q+1 -> pos 32+2q
            o.z = (float)ar[2*q + 1]      * INV + bv.z;   // f=4q+2 -> pos 2q+1
            o.w = (float)ar[32 + 2*q + 1] * INV + bv.w;   // f=4q+3 -> pos 32+2q+1
            out4[row * 16 + q] = o;
        }
    }
}

// ---------------- fallback (small ws): atomic scatter ----------------
__global__ __launch_bounds__(256) void init_out_kernel(const float* __restrict__ b,
                                                       float* __restrict__ out) {
    const int i = blockIdx.x * blockDim.x + threadIdx.x;
    const int total4 = N_NODES * D / 4;
    if (i < total4) {
        const float4* b4 = reinterpret_cast<const float4*>(b);
        reinterpret_cast<float4*>(out)[i] = b4[i & 15];
    }
}

__global__ __launch_bounds__(256) void scatter_kernel(const int* __restrict__ erow,
                                                      const int* __restrict__ ecol,
                                                      const float* __restrict__ eval_,
                                                      const unsigned short* __restrict__ y,
                                                      float* __restrict__ out, int ne) {
    const int e    = blockIdx.x * 4 + (threadIdx.x >> 6);
    const int lane = threadIdx.x & 63;
    if (e >= ne) return;
    atomicAdd(&out[erow[e] * D + lane], eval_[e] * bf16_to_f32(y[ecol[e] * D + lane]));
}

extern "C" void kernel_launch(void* const* d_in, const int* in_sizes, int n_in,
                              void* d_out, int out_size, void* d_ws, size_t ws_size,
                              hipStream_t stream) {
    const float* x     = (const float*)d_in[0];
    const int*   erow  = (const int*)  d_in[1];
    const int*   ecol  = (const int*)  d_in[2];
    const float* eval_ = (const float*)d_in[3];
    const float* W     = (const float*)d_in[4];
    const float* b     = (const float*)d_in[5];
    float*       out   = (float*)d_out;
    const int ne = in_sizes[1];

    char* ws = (char*)d_ws;
    // workspace layout (aligned)
    const size_t Y_OFF     = 0;             // 12,800,000 B
    const size_t PEDGE_OFF = 12800000;      // 4,000,000 B
    const size_t H2D_OFF   = 16800000;      // npb*NBINS*4 (<= 4,000,000 B)
    const size_t SCAN_OFF  = 20800000;      // <= 4,000,000 B
    const size_t BSUM_OFF  = 24800000;      // 8,192 B
    const size_t CNT_OFF   = 24808192;      // 256 B
    const size_t TOTAL     = 24808448;

    unsigned short* y = (unsigned short*)(ws + Y_OFF);

    const int npb      = (ne + PE - 1) / PE;       // 489 @ 1M edges
    const int totalSc  = NBINS * npb;              // 764,307
    const int nblocksA = (totalSc + 1023) / 1024;  // 747

    if (ws_size >= TOTAL && npb <= 639) {
        u32* pedge   = (u32*)(ws + PEDGE_OFF);
        int* hist2d  = (int*)(ws + H2D_OFF);
        int* scan2d  = (int*)(ws + SCAN_OFF);
        int* bsum    = (int*)(ws + BSUM_OFF);
        int* counter = (int*)(ws + CNT_OFF);

        // 1) fused: y = bf16(x @ W^T)  ||  per-block bin histograms  (also zeroes counter)
        xw_hist_kernel<<<XWB + npb, 256, 0, stream>>>(x, W, y, erow, hist2d, counter, ne);

        // 2) bin-major exclusive scan + in-kernel bsum fixup (last block)
        scan_kernel<<<nblocksA, 256, 0, stream>>>(hist2d, scan2d, bsum, counter, totalSc, npb, nblocksA);

        // 3) partition: single store pass, no global atomics
        partition_kernel<<<npb, 256, 0, stream>>>(erow, ecol, eval_, scan2d, bsum, pedge, ne, npb);

        // 4) per-bin aggregation + bias (ushort2 gathers, swizzled LDS acc)
        aggregate_kernel<<<NBINS, 512, 0, stream>>>(scan2d, bsum, pedge, (const u32*)y, b,
                                                    (float4*)out, ne, npb);
    } else {
        xw_hist_kernel<<<XWB, 256, 0, stream>>>(x, W, y, erow, (int*)ws, (int*)ws, 0);
        init_out_kernel<<<(N_NODES * D / 4 + 255) / 256, 256, 0, stream>>>(b, out);
        scatter_kernel<<<(ne + 3) / 4, 256, 0, stream>>>(erow, ecol, eval_, y, out, ne);
    }
}

// Round 12
// 123.590 us; speedup vs baseline: 1.6954x; 1.6954x over previous
//
#include <hip/hip_runtime.h>

#define N_NODES 100000
#define D 64
#define BIN_ROWS 64
#define NBINS 1563          // ceil(100000 / 64)
#define PE 2048             // edges per hist/partition block
#define XWB 3125            // xw blocks (100000 / 32)

typedef unsigned int u32;

__device__ __forceinline__ float bf16_to_f32(unsigned short u) {
    union { u32 i; float f; } c; c.i = ((u32)u) << 16; return c.f;
}
__device__ __forceinline__ unsigned short f32_to_bf16(float f) {
    union { float f; u32 i; } c; c.f = f;
    const u32 u = c.i;
    return (unsigned short)((u + 0x7FFFu + ((u >> 16) & 1u)) >> 16);
}

// ---------------- K1: fused  y = bf16(x @ W^T)  (blocks < XWB)
// ----------------            per-block bin histogram (blocks >= XWB) ----------------
__global__ __launch_bounds__(256) void xw_hist_kernel(const float* __restrict__ x,
                                                      const float* __restrict__ W,
                                                      unsigned short* __restrict__ y,
                                                      const int* __restrict__ erow,
                                                      int* __restrict__ hist2d, int ne) {
    __shared__ union {
        struct { float Ws[D * 68]; float xs[32][D]; } g;
        int h[NBINS];
    } sm;
    const int tid = threadIdx.x;

    if (blockIdx.x >= XWB) {
        // ---- binhist: dense per-block histogram, no global atomics ----
        const int blk = blockIdx.x - XWB;
        for (int i = tid; i < NBINS; i += 256) sm.h[i] = 0;
        __syncthreads();
        const int base = blk * PE;
        const int end  = min(base + PE, ne);
        for (int e = base + tid; e < end; e += 256)
            atomicAdd(&sm.h[erow[e] >> 6], 1);           // LDS, no-return
        __syncthreads();
        for (int i = tid; i < NBINS; i += 256)
            hist2d[blk * NBINS + i] = sm.h[i];           // coalesced
        return;
    }

    // ---- xw: W register-resident, x via LDS broadcast ----
    for (int i = tid; i < D * D; i += 256)
        sm.g.Ws[(i >> 6) * 68 + (i & 63)] = W[i];

    const int nodeBase = blockIdx.x * 32;                // N_NODES = 3125*32 exactly
    for (int i = tid; i < 32 * D; i += 256)
        sm.g.xs[i >> 6][i & 63] = x[(nodeBase + (i >> 6)) * D + (i & 63)];
    __syncthreads();

    const int j = tid & 63, w = tid >> 6;
    float4 wr[16];
    const float4* WsRow = (const float4*)(sm.g.Ws + j * 68);
#pragma unroll
    for (int k = 0; k < 16; ++k) wr[k] = WsRow[k];

    for (int s = 0; s < 8; ++s) {
        const int local = w * 8 + s;
        const float4* xr = (const float4*)(&sm.g.xs[local][0]);
        float a0 = 0.f, a1 = 0.f, a2 = 0.f, a3 = 0.f;
#pragma unroll
        for (int k = 0; k < 16; k += 4) {
            const float4 x0 = xr[k], x1 = xr[k+1], x2 = xr[k+2], x3 = xr[k+3];
            a0 = fmaf(x0.x, wr[k].x, a0);   a0 = fmaf(x0.y, wr[k].y, a0);
            a0 = fmaf(x0.z, wr[k].z, a0);   a0 = fmaf(x0.w, wr[k].w, a0);
            a1 = fmaf(x1.x, wr[k+1].x, a1); a1 = fmaf(x1.y, wr[k+1].y, a1);
            a1 = fmaf(x1.z, wr[k+1].z, a1); a1 = fmaf(x1.w, wr[k+1].w, a1);
            a2 = fmaf(x2.x, wr[k+2].x, a2); a2 = fmaf(x2.y, wr[k+2].y, a2);
            a2 = fmaf(x2.z, wr[k+2].z, a2); a2 = fmaf(x2.w, wr[k+2].w, a2);
            a3 = fmaf(x3.x, wr[k+3].x, a3); a3 = fmaf(x3.y, wr[k+3].y, a3);
            a3 = fmaf(x3.z, wr[k+3].z, a3); a3 = fmaf(x3.w, wr[k+3].w, a3);
        }
        y[(nodeBase + local) * D + j] = f32_to_bf16((a0 + a1) + (a2 + a3));
    }
}

// ---------------- scanA: per-1024-chunk exclusive scan (bin-major index) + chunk sums ----------------
__global__ __launch_bounds__(256) void scanA_kernel(const int* __restrict__ hist2d,
                                                    int* __restrict__ scan2d,
                                                    int* __restrict__ bsum,
                                                    int total, int npb) {
    __shared__ int sdat[256];
    const int tid  = threadIdx.x;
    const int base = blockIdx.x * 1024 + tid * 4;
    int v[4], sum = 0;
    int bin = 0, blk = 0;
    if (base < total) { bin = base / npb; blk = base - bin * npb; }
#pragma unroll
    for (int k = 0; k < 4; ++k) {
        const int idx = base + k;
        v[k] = (idx < total) ? hist2d[blk * NBINS + bin] : 0;
        sum += v[k];
        if (++blk == npb) { blk = 0; ++bin; }
    }
    sdat[tid] = sum;
    __syncthreads();
    for (int d = 1; d < 256; d <<= 1) {
        const int t = (tid >= d) ? sdat[tid - d] : 0;
        __syncthreads();
        sdat[tid] += t;
        __syncthreads();
    }
    int run = sdat[tid] - sum;
#pragma unroll
    for (int k = 0; k < 4; ++k) {
        const int idx = base + k;
        if (idx < total) scan2d[idx] = run;
        run += v[k];
    }
    if (tid == 255) bsum[blockIdx.x] = sdat[255];
}

// ---------------- scanB: single-block exclusive scan of chunk sums (in place) ----------------
__global__ __launch_bounds__(1024) void scanB_kernel(int* __restrict__ bsum, int nb) {
    __shared__ int s[1024];
    const int tid = threadIdx.x;
    const int a = (2 * tid     < nb) ? bsum[2 * tid]     : 0;
    const int b = (2 * tid + 1 < nb) ? bsum[2 * tid + 1] : 0;
    const int pair = a + b;
    s[tid] = pair;
    __syncthreads();
    for (int d = 1; d < 1024; d <<= 1) {
        const int t = (tid >= d) ? s[tid - d] : 0;
        __syncthreads();
        s[tid] += t;
        __syncthreads();
    }
    const int excl = s[tid] - pair;
    if (2 * tid     < nb) bsum[2 * tid]     = excl;
    if (2 * tid + 1 < nb) bsum[2 * tid + 1] = excl + a;
}

// ---------------- partition: precomputed cursors (scan2d + bsum), single store pass ----------------
__global__ __launch_bounds__(256) void partition_kernel(const int* __restrict__ erow,
                                                        const int* __restrict__ ecol,
                                                        const float* __restrict__ eval_,
                                                        const int* __restrict__ scan2d,
                                                        const int* __restrict__ bsum,
                                                        u32* __restrict__ pedge,
                                                        int ne, int npb) {
    __shared__ int lcur[NBINS];
    const int blk = blockIdx.x;
    for (int i = threadIdx.x; i < NBINS; i += 256) {
        const int idx = i * npb + blk;
        lcur[i] = scan2d[idx] + bsum[idx >> 10];
    }
    __syncthreads();
    const int base = blk * PE;
    const int end  = min(base + PE, ne);
    for (int e = base + threadIdx.x; e < end; e += 256) {
        const int r   = erow[e];
        const int bin = r >> 6;
        const int pos = atomicAdd(&lcur[bin], 1);    // LDS-local rank
        int q = (int)(eval_[e] * 512.0f + 0.5f);
        q = (q > 511) ? 511 : q;
        pedge[pos] = ((u32)ecol[e] << 15) | ((u32)(r & 63) << 9) | (u32)q;
    }
}

// ---------------- aggregate: ushort2 gathers, swizzled 16KB int LDS acc ----------------
// acc position for feature f: ((f&1)<<5) | (f>>1)  -> both ds_adds land on bank (lane&31)
__global__ __launch_bounds__(512) void aggregate_kernel(const int* __restrict__ scan2d,
                                                        const int* __restrict__ bsum,
                                                        const u32* __restrict__ pedge,
                                                        const u32* __restrict__ y2,
                                                        const float* __restrict__ b,
                                                        float4* __restrict__ out4,
                                                        int ne, int npb) {
    __shared__ int acc[BIN_ROWS * D];    // 16 KB
    const int tid = threadIdx.x;
    for (int i = tid; i < BIN_ROWS * D; i += 512) acc[i] = 0;
    __syncthreads();

    const int bin = blockIdx.x;
    const int hl  = tid & 31;            // u32 slot within row (features 2hl, 2hl+1)
    const int hi  = (tid >> 5) & 1;      // which edge of the pair
    const int w   = tid >> 6;            // 0..7
    const int i0  = bin * npb;
    const int s   = scan2d[i0] + bsum[i0 >> 10];
    int e;
    if (bin + 1 < NBINS) { const int i1 = (bin + 1) * npb; e = scan2d[i1] + bsum[i1 >> 10]; }
    else e = ne;

    for (int bb0 = s + w * 16; bb0 < e; bb0 += 128) {
        const int bb = __builtin_amdgcn_readfirstlane(bb0);
        u32 u[16];
        if (bb + 16 <= e) {
#pragma unroll
            for (int j = 0; j < 16; ++j) u[j] = pedge[bb + j];   // uniform -> s_load
        } else {
#pragma unroll
            for (int j = 0; j < 16; ++j) {
                const int idx = bb + j;
                u[j] = (idx < e) ? pedge[idx] : 0u;              // pad adds 0
            }
        }
        u32 ue[8], g2[8];
#pragma unroll
        for (int p = 0; p < 8; ++p) {                            // 8 gathers, 2 edges each
            ue[p] = hi ? u[2*p + 1] : u[2*p];
            g2[p] = y2[(ue[p] >> 15) * 32 + hl];                 // 4B/lane, 256B/inst
        }
#pragma unroll
        for (int p = 0; p < 8; ++p) {
            const float vq  = (float)(ue[p] & 511u);             // val * 512
            const int   r   = (int)((ue[p] >> 9) & 63u);
            const float ylo = bf16_to_f32((unsigned short)(g2[p] & 0xFFFFu));
            const float yhi = bf16_to_f32((unsigned short)(g2[p] >> 16));
            atomicAdd(&acc[r * 64 + hl],      (int)(vq * ylo * 512.0f));  // bank = hl
            atomicAdd(&acc[r * 64 + 32 + hl], (int)(vq * yhi * 512.0f));  // bank = hl
        }
    }
    __syncthreads();

    const int rowBase = bin * BIN_ROWS;
    const float INV = 1.0f / 262144.0f;
    for (int i = tid; i < BIN_ROWS * 16; i += 512) {
        const int rl = i >> 4, q = i & 15;
        const int row = rowBase + rl;
        if (row < N_NODES) {
            const float4 bv = ((const float4*)b)[q];
            const int* ar = &acc[rl * 64];
            float4 o;
            o.x = (float)ar[2*q]          * INV + bv.x;   // f=4q   -> pos 2q
            o.y = (float)ar[32 + 2*q]     * INV + bv.y;   // f=4q+1 -> pos 32+2q
            o.z = (float)ar[2*q + 1]      * INV + bv.z;   // f=4q+2 -> pos 2q+1
            o.w = (float)ar[32 + 2*q + 1] * INV + bv.w;   // f=4q+3 -> pos 32+2q+1
            out4[row * 16 + q] = o;
        }
    }
}

// ---------------- fallback (small ws): atomic scatter ----------------
__global__ __launch_bounds__(256) void init_out_kernel(const float* __restrict__ b,
                                                       float* __restrict__ out) {
    const int i = blockIdx.x * blockDim.x + threadIdx.x;
    const int total4 = N_NODES * D / 4;
    if (i < total4) {
        const float4* b4 = reinterpret_cast<const float4*>(b);
        reinterpret_cast<float4*>(out)[i] = b4[i & 15];
    }
}

__global__ __launch_bounds__(256) void scatter_kernel(const int* __restrict__ erow,
                                                      const int* __restrict__ ecol,
                                                      const float* __restrict__ eval_,
                                                      const unsigned short* __restrict__ y,
                                                      float* __restrict__ out, int ne) {
    const int e    = blockIdx.x * 4 + (threadIdx.x >> 6);
    const int lane = threadIdx.x & 63;
    if (e >= ne) return;
    atomicAdd(&out[erow[e] * D + lane], eval_[e] * bf16_to_f32(y[ecol[e] * D + lane]));
}

extern "C" void kernel_launch(void* const* d_in, const int* in_sizes, int n_in,
                              void* d_out, int out_size, void* d_ws, size_t ws_size,
                              hipStream_t stream) {
    const float* x     = (const float*)d_in[0];
    const int*   erow  = (const int*)  d_in[1];
    const int*   ecol  = (const int*)  d_in[2];
    const float* eval_ = (const float*)d_in[3];
    const float* W     = (const float*)d_in[4];
    const float* b     = (const float*)d_in[5];
    float*       out   = (float*)d_out;
    const int ne = in_sizes[1];

    char* ws = (char*)d_ws;
    // workspace layout (aligned)
    const size_t Y_OFF     = 0;             // 12,800,000 B
    const size_t PEDGE_OFF = 12800000;      // 4,000,000 B
    const size_t H2D_OFF   = 16800000;      // npb*NBINS*4 (<= 4,000,000 B)
    const size_t SCAN_OFF  = 20800000;      // <= 4,000,000 B
    const size_t BSUM_OFF  = 24800000;      // 8,192 B
    const size_t TOTAL     = 24808192;

    unsigned short* y = (unsigned short*)(ws + Y_OFF);

    const int npb      = (ne + PE - 1) / PE;       // 489 @ 1M edges
    const int totalSc  = NBINS * npb;              // 764,307
    const int nblocksA = (totalSc + 1023) / 1024;  // 747 (<= 2048 for scanB)

    if (ws_size >= TOTAL && npb <= 1341) {
        u32* pedge  = (u32*)(ws + PEDGE_OFF);
        int* hist2d = (int*)(ws + H2D_OFF);
        int* scan2d = (int*)(ws + SCAN_OFF);
        int* bsum   = (int*)(ws + BSUM_OFF);

        // 1) fused: y = bf16(x @ W^T)  ||  per-block bin histograms
        xw_hist_kernel<<<XWB + npb, 256, 0, stream>>>(x, W, y, erow, hist2d, ne);

        // 2) bin-major exclusive scan (two kernels — NO device fences, see r11 post-mortem)
        scanA_kernel<<<nblocksA, 256, 0, stream>>>(hist2d, scan2d, bsum, totalSc, npb);
        scanB_kernel<<<1, 1024, 0, stream>>>(bsum, nblocksA);

        // 3) partition: single store pass, no global atomics
        partition_kernel<<<npb, 256, 0, stream>>>(erow, ecol, eval_, scan2d, bsum, pedge, ne, npb);

        // 4) per-bin aggregation + bias (ushort2 gathers, swizzled LDS acc)
        aggregate_kernel<<<NBINS, 512, 0, stream>>>(scan2d, bsum, pedge, (const u32*)y, b,
                                                    (float4*)out, ne, npb);
    } else {
        xw_hist_kernel<<<XWB, 256, 0, stream>>>(x, W, y, erow, (int*)ws, 0);
        init_out_kernel<<<(N_NODES * D / 4 + 255) / 256, 256, 0, stream>>>(b, out);
        scatter_kernel<<<(ne + 3) / 4, 256, 0, stream>>>(erow, ecol, eval_, y, out, ne);
    }
}

// Round 13
// 79.435 us; speedup vs baseline: 2.6378x; 1.5559x over previous
//
#include <hip/hip_runtime.h>

#define N_NODES 100000
#define D 64
#define BIN_ROWS 64
#define NBINS 1563          // ceil(100000 / 64)
#define PE 2048             // edges per hist/partition block
#define XWB 3125            // xw blocks (100000 / 32)

typedef unsigned int u32;

__device__ __forceinline__ float bf16_to_f32(unsigned short u) {
    union { u32 i; float f; } c; c.i = ((u32)u) << 16; return c.f;
}
__device__ __forceinline__ unsigned short f32_to_bf16(float f) {
    union { float f; u32 i; } c; c.f = f;
    const u32 u = c.i;
    return (unsigned short)((u + 0x7FFFu + ((u >> 16) & 1u)) >> 16);
}

// ---------------- K1: fused  y = bf16(x @ W^T)  (blocks < XWB)
// ----------------            per-block bin histogram (blocks >= XWB) ----------------
__global__ __launch_bounds__(256) void xw_hist_kernel(const float* __restrict__ x,
                                                      const float* __restrict__ W,
                                                      unsigned short* __restrict__ y,
                                                      const int* __restrict__ erow,
                                                      int* __restrict__ hist2d, int ne) {
    __shared__ union {
        struct { float Ws[D * 68]; float xs[32][D]; } g;
        int h[NBINS];
    } sm;
    const int tid = threadIdx.x;

    if (blockIdx.x >= XWB) {
        // ---- binhist: dense per-block histogram, no global atomics ----
        const int blk = blockIdx.x - XWB;
        for (int i = tid; i < NBINS; i += 256) sm.h[i] = 0;
        __syncthreads();
        const int base = blk * PE;
        const int end  = min(base + PE, ne);
        for (int e = base + tid; e < end; e += 256)
            atomicAdd(&sm.h[erow[e] >> 6], 1);           // LDS, no-return
        __syncthreads();
        for (int i = tid; i < NBINS; i += 256)
            hist2d[blk * NBINS + i] = sm.h[i];           // coalesced
        return;
    }

    // ---- xw: W register-resident, x via LDS broadcast ----
    for (int i = tid; i < D * D; i += 256)
        sm.g.Ws[(i >> 6) * 68 + (i & 63)] = W[i];

    const int nodeBase = blockIdx.x * 32;                // N_NODES = 3125*32 exactly
    for (int i = tid; i < 32 * D; i += 256)
        sm.g.xs[i >> 6][i & 63] = x[(nodeBase + (i >> 6)) * D + (i & 63)];
    __syncthreads();

    const int j = tid & 63, w = tid >> 6;
    float4 wr[16];
    const float4* WsRow = (const float4*)(sm.g.Ws + j * 68);
#pragma unroll
    for (int k = 0; k < 16; ++k) wr[k] = WsRow[k];

    for (int s = 0; s < 8; ++s) {
        const int local = w * 8 + s;
        const float4* xr = (const float4*)(&sm.g.xs[local][0]);
        float a0 = 0.f, a1 = 0.f, a2 = 0.f, a3 = 0.f;
#pragma unroll
        for (int k = 0; k < 16; k += 4) {
            const float4 x0 = xr[k], x1 = xr[k+1], x2 = xr[k+2], x3 = xr[k+3];
            a0 = fmaf(x0.x, wr[k].x, a0);   a0 = fmaf(x0.y, wr[k].y, a0);
            a0 = fmaf(x0.z, wr[k].z, a0);   a0 = fmaf(x0.w, wr[k].w, a0);
            a1 = fmaf(x1.x, wr[k+1].x, a1); a1 = fmaf(x1.y, wr[k+1].y, a1);
            a1 = fmaf(x1.z, wr[k+1].z, a1); a1 = fmaf(x1.w, wr[k+1].w, a1);
            a2 = fmaf(x2.x, wr[k+2].x, a2); a2 = fmaf(x2.y, wr[k+2].y, a2);
            a2 = fmaf(x2.z, wr[k+2].z, a2); a2 = fmaf(x2.w, wr[k+2].w, a2);
            a3 = fmaf(x3.x, wr[k+3].x, a3); a3 = fmaf(x3.y, wr[k+3].y, a3);
            a3 = fmaf(x3.z, wr[k+3].z, a3); a3 = fmaf(x3.w, wr[k+3].w, a3);
        }
        y[(nodeBase + local) * D + j] = f32_to_bf16((a0 + a1) + (a2 + a3));
    }
}

// ---------------- scanA: per-1024-chunk exclusive scan (bin-major index) + chunk sums ----------------
__global__ __launch_bounds__(256) void scanA_kernel(const int* __restrict__ hist2d,
                                                    int* __restrict__ scan2d,
                                                    int* __restrict__ bsum,
                                                    int total, int npb) {
    __shared__ int sdat[256];
    const int tid  = threadIdx.x;
    const int base = blockIdx.x * 1024 + tid * 4;
    int v[4], sum = 0;
    int bin = 0, blk = 0;
    if (base < total) { bin = base / npb; blk = base - bin * npb; }
#pragma unroll
    for (int k = 0; k < 4; ++k) {
        const int idx = base + k;
        v[k] = (idx < total) ? hist2d[blk * NBINS + bin] : 0;
        sum += v[k];
        if (++blk == npb) { blk = 0; ++bin; }
    }
    sdat[tid] = sum;
    __syncthreads();
    for (int d = 1; d < 256; d <<= 1) {
        const int t = (tid >= d) ? sdat[tid - d] : 0;
        __syncthreads();
        sdat[tid] += t;
        __syncthreads();
    }
    int run = sdat[tid] - sum;
#pragma unroll
    for (int k = 0; k < 4; ++k) {
        const int idx = base + k;
        if (idx < total) scan2d[idx] = run;
        run += v[k];
    }
    if (tid == 255) bsum[blockIdx.x] = sdat[255];
}

// ---------------- scanB: single-block exclusive scan of chunk sums (in place) ----------------
__global__ __launch_bounds__(1024) void scanB_kernel(int* __restrict__ bsum, int nb) {
    __shared__ int s[1024];
    const int tid = threadIdx.x;
    const int a = (2 * tid     < nb) ? bsum[2 * tid]     : 0;
    const int b = (2 * tid + 1 < nb) ? bsum[2 * tid + 1] : 0;
    const int pair = a + b;
    s[tid] = pair;
    __syncthreads();
    for (int d = 1; d < 1024; d <<= 1) {
        const int t = (tid >= d) ? s[tid - d] : 0;
        __syncthreads();
        s[tid] += t;
        __syncthreads();
    }
    const int excl = s[tid] - pair;
    if (2 * tid     < nb) bsum[2 * tid]     = excl;
    if (2 * tid + 1 < nb) bsum[2 * tid + 1] = excl + a;
}

// ---------------- partition: precomputed cursors, single store pass (512 thr) ----------------
__global__ __launch_bounds__(512) void partition_kernel(const int* __restrict__ erow,
                                                        const int* __restrict__ ecol,
                                                        const float* __restrict__ eval_,
                                                        const int* __restrict__ scan2d,
                                                        const int* __restrict__ bsum,
                                                        u32* __restrict__ pedge,
                                                        int ne, int npb) {
    __shared__ int lcur[NBINS];
    const int blk = blockIdx.x;
    for (int i = threadIdx.x; i < NBINS; i += 512) {
        const int idx = i * npb + blk;
        lcur[i] = scan2d[idx] + bsum[idx >> 10];
    }
    __syncthreads();
    const int base = blk * PE;
    const int end  = min(base + PE, ne);
    for (int e = base + threadIdx.x; e < end; e += 512) {
        const int r   = erow[e];
        const int bin = r >> 6;
        const int pos = atomicAdd(&lcur[bin], 1);    // LDS-local rank
        int q = (int)(eval_[e] * 512.0f + 0.5f);
        q = (q > 511) ? 511 : q;
        pedge[pos] = ((u32)ecol[e] << 15) | ((u32)(r & 63) << 9) | (u32)q;
    }
}

// ---------------- aggregate: round-10 form (register-clean), 512 thr, 16KB int LDS acc ----------------
__global__ __launch_bounds__(512) void aggregate_kernel(const int* __restrict__ scan2d,
                                                        const int* __restrict__ bsum,
                                                        const u32* __restrict__ pedge,
                                                        const unsigned short* __restrict__ y,
                                                        const float* __restrict__ b,
                                                        float4* __restrict__ out4,
                                                        int ne, int npb) {
    __shared__ int acc[BIN_ROWS * D];    // 16 KB
    const int tid = threadIdx.x;
    for (int i = tid; i < BIN_ROWS * D; i += 512) acc[i] = 0;
    __syncthreads();

    const int bin  = blockIdx.x;
    const int lane = tid & 63;
    const int w    = tid >> 6;           // 0..7
    const int i0   = bin * npb;
    const int s    = scan2d[i0] + bsum[i0 >> 10];
    int e;
    if (bin + 1 < NBINS) { const int i1 = (bin + 1) * npb; e = scan2d[i1] + bsum[i1 >> 10]; }
    else e = ne;

    for (int bb0 = s + w * 16; bb0 < e; bb0 += 128) {
        const int bb = __builtin_amdgcn_readfirstlane(bb0);
        u32 u[16];
        if (bb + 16 <= e) {
#pragma unroll
            for (int j = 0; j < 16; ++j) u[j] = pedge[bb + j];   // uniform -> s_load
        } else {
#pragma unroll
            for (int j = 0; j < 16; ++j) {
                const int idx = bb + j;
                u[j] = (idx < e) ? pedge[idx] : 0u;              // pad adds 0
            }
        }
        unsigned short g[16];
#pragma unroll
        for (int j = 0; j < 16; ++j) {                           // 16 concurrent 128B gathers
            g[j] = y[(int)(u[j] >> 15) * D + lane];
        }
#pragma unroll
        for (int j = 0; j < 16; ++j) {
            const float vq = (float)(u[j] & 511u);               // val * 512
            const float yf = bf16_to_f32(g[j]);
            const int   qi = (int)(vq * yf * 512.0f);            // contribution * 2^18
            const int   r  = (int)((u[j] >> 9) & 63u);
            atomicAdd(&acc[r * D + lane], qi);                   // ds_add_u32 (native)
        }
    }
    __syncthreads();

    const int rowBase = bin * BIN_ROWS;
    const float INV = 1.0f / 262144.0f;
    for (int i = tid; i < BIN_ROWS * 16; i += 512) {
        const int rl = i >> 4, q = i & 15;
        const int row = rowBase + rl;
        if (row < N_NODES) {
            const int4   a  = ((const int4*)acc)[i];
            const float4 bv = ((const float4*)b)[q];
            out4[row * 16 + q] = make_float4((float)a.x * INV + bv.x,
                                             (float)a.y * INV + bv.y,
                                             (float)a.z * INV + bv.z,
                                             (float)a.w * INV + bv.w);
        }
    }
}

// ---------------- fallback (small ws): atomic scatter ----------------
__global__ __launch_bounds__(256) void init_out_kernel(const float* __restrict__ b,
                                                       float* __restrict__ out) {
    const int i = blockIdx.x * blockDim.x + threadIdx.x;
    const int total4 = N_NODES * D / 4;
    if (i < total4) {
        const float4* b4 = reinterpret_cast<const float4*>(b);
        reinterpret_cast<float4*>(out)[i] = b4[i & 15];
    }
}

__global__ __launch_bounds__(256) void scatter_kernel(const int* __restrict__ erow,
                                                      const int* __restrict__ ecol,
                                                      const float* __restrict__ eval_,
                                                      const unsigned short* __restrict__ y,
                                                      float* __restrict__ out, int ne) {
    const int e    = blockIdx.x * 4 + (threadIdx.x >> 6);
    const int lane = threadIdx.x & 63;
    if (e >= ne) return;
    atomicAdd(&out[erow[e] * D + lane], eval_[e] * bf16_to_f32(y[ecol[e] * D + lane]));
}

extern "C" void kernel_launch(void* const* d_in, const int* in_sizes, int n_in,
                              void* d_out, int out_size, void* d_ws, size_t ws_size,
                              hipStream_t stream) {
    const float* x     = (const float*)d_in[0];
    const int*   erow  = (const int*)  d_in[1];
    const int*   ecol  = (const int*)  d_in[2];
    const float* eval_ = (const float*)d_in[3];
    const float* W     = (const float*)d_in[4];
    const float* b     = (const float*)d_in[5];
    float*       out   = (float*)d_out;
    const int ne = in_sizes[1];

    char* ws = (char*)d_ws;
    // workspace layout (aligned)
    const size_t Y_OFF     = 0;             // 12,800,000 B
    const size_t PEDGE_OFF = 12800000;      // 4,000,000 B
    const size_t H2D_OFF   = 16800000;      // npb*NBINS*4 (<= 4,000,000 B)
    const size_t SCAN_OFF  = 20800000;      // <= 4,000,000 B
    const size_t BSUM_OFF  = 24800000;      // 8,192 B
    const size_t TOTAL     = 24808192;

    unsigned short* y = (unsigned short*)(ws + Y_OFF);

    const int npb      = (ne + PE - 1) / PE;       // 489 @ 1M edges
    const int totalSc  = NBINS * npb;              // 764,307
    const int nblocksA = (totalSc + 1023) / 1024;  // 747 (<= 2048 for scanB)

    if (ws_size >= TOTAL && npb <= 1341) {
        u32* pedge  = (u32*)(ws + PEDGE_OFF);
        int* hist2d = (int*)(ws + H2D_OFF);
        int* scan2d = (int*)(ws + SCAN_OFF);
        int* bsum   = (int*)(ws + BSUM_OFF);

        // 1) fused: y = bf16(x @ W^T)  ||  per-block bin histograms
        xw_hist_kernel<<<XWB + npb, 256, 0, stream>>>(x, W, y, erow, hist2d, ne);

        // 2) bin-major exclusive scan (two kernels — NO device fences, r11 post-mortem)
        scanA_kernel<<<nblocksA, 256, 0, stream>>>(hist2d, scan2d, bsum, totalSc, npb);
        scanB_kernel<<<1, 1024, 0, stream>>>(bsum, nblocksA);

        // 3) partition: single store pass, no global atomics
        partition_kernel<<<npb, 512, 0, stream>>>(erow, ecol, eval_, scan2d, bsum, pedge, ne, npb);

        // 4) per-bin aggregation + bias (round-10 register-clean form)
        aggregate_kernel<<<NBINS, 512, 0, stream>>>(scan2d, bsum, pedge, y, b, (float4*)out, ne, npb);
    } else {
        xw_hist_kernel<<<XWB, 256, 0, stream>>>(x, W, y, erow, (int*)ws, 0);
        init_out_kernel<<<(N_NODES * D / 4 + 255) / 256, 256, 0, stream>>>(b, out);
        scatter_kernel<<<(ne + 3) / 4, 256, 0, stream>>>(erow, ecol, eval_, y, out, ne);
    }
}

// Round 14
// 75.004 us; speedup vs baseline: 2.7937x; 1.0591x over previous
//
#include <hip/hip_runtime.h>

#define N_NODES 100000
#define D 64
#define BIN_ROWS 64
#define NBINS 1563          // ceil(100000 / 64)
#define PE 2048             // edges per hist/partition block
#define XWB 3125            // xw blocks (100000 / 32)

typedef unsigned int u32;

__device__ __forceinline__ float bf16_to_f32(unsigned short u) {
    union { u32 i; float f; } c; c.i = ((u32)u) << 16; return c.f;
}
__device__ __forceinline__ unsigned short f32_to_bf16(float f) {
    union { float f; u32 i; } c; c.f = f;
    const u32 u = c.i;
    return (unsigned short)((u + 0x7FFFu + ((u >> 16) & 1u)) >> 16);
}

// ---------------- K1: per-block LDS histogram -> dense hist2d[blk][NBINS] ----------------
__global__ __launch_bounds__(256) void hist_kernel(const int* __restrict__ erow,
                                                   int* __restrict__ hist2d, int ne) {
    __shared__ int h[NBINS];
    const int tid = threadIdx.x;
    for (int i = tid; i < NBINS; i += 256) h[i] = 0;
    __syncthreads();
    const int base = blockIdx.x * PE;
    const int end  = min(base + PE, ne);
    for (int e = base + tid; e < end; e += 256)
        atomicAdd(&h[erow[e] >> 6], 1);              // LDS, no-return
    __syncthreads();
    for (int i = tid; i < NBINS; i += 256)
        hist2d[blockIdx.x * NBINS + i] = h[i];       // coalesced
}

// ---------------- K2: scanA — per-1024-chunk exclusive scan (bin-major) + chunk sums ----------------
__global__ __launch_bounds__(256) void scanA_kernel(const int* __restrict__ hist2d,
                                                    int* __restrict__ scan2d,
                                                    int* __restrict__ bsum,
                                                    int total, int npb) {
    __shared__ int sdat[256];
    const int tid  = threadIdx.x;
    const int base = blockIdx.x * 1024 + tid * 4;
    int v[4], sum = 0;
    int bin = 0, blk = 0;
    if (base < total) { bin = base / npb; blk = base - bin * npb; }
#pragma unroll
    for (int k = 0; k < 4; ++k) {
        const int idx = base + k;
        v[k] = (idx < total) ? hist2d[blk * NBINS + bin] : 0;
        sum += v[k];
        if (++blk == npb) { blk = 0; ++bin; }
    }
    sdat[tid] = sum;
    __syncthreads();
    for (int d = 1; d < 256; d <<= 1) {
        const int t = (tid >= d) ? sdat[tid - d] : 0;
        __syncthreads();
        sdat[tid] += t;
        __syncthreads();
    }
    int run = sdat[tid] - sum;
#pragma unroll
    for (int k = 0; k < 4; ++k) {
        const int idx = base + k;
        if (idx < total) scan2d[idx] = run;
        run += v[k];
    }
    if (tid == 255) bsum[blockIdx.x] = sdat[255];
}

// ---------------- K3: scanB — single-block exclusive scan of chunk sums (in place) ----------------
__global__ __launch_bounds__(1024) void scanB_kernel(int* __restrict__ bsum, int nb) {
    __shared__ int s[1024];
    const int tid = threadIdx.x;
    const int a = (2 * tid     < nb) ? bsum[2 * tid]     : 0;
    const int b = (2 * tid + 1 < nb) ? bsum[2 * tid + 1] : 0;
    const int pair = a + b;
    s[tid] = pair;
    __syncthreads();
    for (int d = 1; d < 1024; d <<= 1) {
        const int t = (tid >= d) ? s[tid - d] : 0;
        __syncthreads();
        s[tid] += t;
        __syncthreads();
    }
    const int excl = s[tid] - pair;
    if (2 * tid     < nb) bsum[2 * tid]     = excl;
    if (2 * tid + 1 < nb) bsum[2 * tid + 1] = excl + a;
}

// ---------------- K4: fused  partition (blocks < npb)  ||  xw (blocks >= npb) ----------------
__global__ __launch_bounds__(256) void xw_part_kernel(const float* __restrict__ x,
                                                      const float* __restrict__ W,
                                                      unsigned short* __restrict__ y,
                                                      const int* __restrict__ erow,
                                                      const int* __restrict__ ecol,
                                                      const float* __restrict__ eval_,
                                                      const int* __restrict__ scan2d,
                                                      const int* __restrict__ bsum,
                                                      u32* __restrict__ pedge,
                                                      int* __restrict__ binStart,
                                                      int ne, int npb) {
    __shared__ union {
        struct { float Ws[D * 68]; float xs[32][D]; } g;   // 25.6 KB
        int lcur[NBINS];                                   // 6.3 KB
    } sm;
    const int tid = threadIdx.x;

    if ((int)blockIdx.x < npb) {
        // ---- partition: precomputed cursors, single store pass ----
        const int blk = blockIdx.x;
        for (int i = tid; i < NBINS; i += 256) {
            const int idx = i * npb + blk;
            const int v = scan2d[idx] + bsum[idx >> 10];
            sm.lcur[i] = v;
            if (blk == 0) binStart[i] = v;                 // bin global starts (for aggregate)
        }
        if (blk == 0 && tid == 0) binStart[NBINS] = ne;
        __syncthreads();
        const int base = blk * PE;
        const int end  = min(base + PE, ne);
        for (int e = base + tid; e < end; e += 256) {
            const int r   = erow[e];
            const int bin = r >> 6;
            const int pos = atomicAdd(&sm.lcur[bin], 1);   // LDS-local rank
            int q = (int)(eval_[e] * 512.0f + 0.5f);
            q = (q > 511) ? 511 : q;
            pedge[pos] = ((u32)ecol[e] << 15) | ((u32)(r & 63) << 9) | (u32)q;
        }
        return;
    }

    // ---- xw: W register-resident, x via LDS broadcast ----
    const int bx = blockIdx.x - npb;
    for (int i = tid; i < D * D; i += 256)
        sm.g.Ws[(i >> 6) * 68 + (i & 63)] = W[i];

    const int nodeBase = bx * 32;                          // N_NODES = 3125*32 exactly
    for (int i = tid; i < 32 * D; i += 256)
        sm.g.xs[i >> 6][i & 63] = x[(nodeBase + (i >> 6)) * D + (i & 63)];
    __syncthreads();

    const int j = tid & 63, w = tid >> 6;
    float4 wr[16];
    const float4* WsRow = (const float4*)(sm.g.Ws + j * 68);
#pragma unroll
    for (int k = 0; k < 16; ++k) wr[k] = WsRow[k];

    for (int s = 0; s < 8; ++s) {
        const int local = w * 8 + s;
        const float4* xr = (const float4*)(&sm.g.xs[local][0]);
        float a0 = 0.f, a1 = 0.f, a2 = 0.f, a3 = 0.f;
#pragma unroll
        for (int k = 0; k < 16; k += 4) {
            const float4 x0 = xr[k], x1 = xr[k+1], x2 = xr[k+2], x3 = xr[k+3];
            a0 = fmaf(x0.x, wr[k].x, a0);   a0 = fmaf(x0.y, wr[k].y, a0);
            a0 = fmaf(x0.z, wr[k].z, a0);   a0 = fmaf(x0.w, wr[k].w, a0);
            a1 = fmaf(x1.x, wr[k+1].x, a1); a1 = fmaf(x1.y, wr[k+1].y, a1);
            a1 = fmaf(x1.z, wr[k+1].z, a1); a1 = fmaf(x1.w, wr[k+1].w, a1);
            a2 = fmaf(x2.x, wr[k+2].x, a2); a2 = fmaf(x2.y, wr[k+2].y, a2);
            a2 = fmaf(x2.z, wr[k+2].z, a2); a2 = fmaf(x2.w, wr[k+2].w, a2);
            a3 = fmaf(x3.x, wr[k+3].x, a3); a3 = fmaf(x3.y, wr[k+3].y, a3);
            a3 = fmaf(x3.z, wr[k+3].z, a3); a3 = fmaf(x3.w, wr[k+3].w, a3);
        }
        y[(nodeBase + local) * D + j] = f32_to_bf16((a0 + a1) + (a2 + a3));
    }
}

// ---------------- K5: aggregate — round-10 register-clean form, binStart offsets ----------------
__global__ __launch_bounds__(512) void aggregate_kernel(const int* __restrict__ binStart,
                                                        const u32* __restrict__ pedge,
                                                        const unsigned short* __restrict__ y,
                                                        const float* __restrict__ b,
                                                        float4* __restrict__ out4) {
    __shared__ int acc[BIN_ROWS * D];    // 16 KB
    const int tid = threadIdx.x;
    for (int i = tid; i < BIN_ROWS * D; i += 512) acc[i] = 0;
    __syncthreads();

    const int bin  = blockIdx.x;
    const int lane = tid & 63;
    const int w    = tid >> 6;           // 0..7
    const int s    = binStart[bin];
    const int e    = binStart[bin + 1];

    for (int bb0 = s + w * 16; bb0 < e; bb0 += 128) {
        const int bb = __builtin_amdgcn_readfirstlane(bb0);
        u32 u[16];
        if (bb + 16 <= e) {
#pragma unroll
            for (int j = 0; j < 16; ++j) u[j] = pedge[bb + j];   // uniform -> s_load
        } else {
#pragma unroll
            for (int j = 0; j < 16; ++j) {
                const int idx = bb + j;
                u[j] = (idx < e) ? pedge[idx] : 0u;              // pad adds 0
            }
        }
        unsigned short g[16];
#pragma unroll
        for (int j = 0; j < 16; ++j) {                           // 16 concurrent 128B gathers
            g[j] = y[(int)(u[j] >> 15) * D + lane];
        }
#pragma unroll
        for (int j = 0; j < 16; ++j) {
            const float vq = (float)(u[j] & 511u);               // val * 512
            const float yf = bf16_to_f32(g[j]);
            const int   qi = (int)(vq * yf * 512.0f);            // contribution * 2^18
            const int   r  = (int)((u[j] >> 9) & 63u);
            atomicAdd(&acc[r * D + lane], qi);                   // ds_add_u32 (native)
        }
    }
    __syncthreads();

    const int rowBase = bin * BIN_ROWS;
    const float INV = 1.0f / 262144.0f;
    for (int i = tid; i < BIN_ROWS * 16; i += 512) {
        const int rl = i >> 4, q = i & 15;
        const int row = rowBase + rl;
        if (row < N_NODES) {
            const int4   a  = ((const int4*)acc)[i];
            const float4 bv = ((const float4*)b)[q];
            out4[row * 16 + q] = make_float4((float)a.x * INV + bv.x,
                                             (float)a.y * INV + bv.y,
                                             (float)a.z * INV + bv.z,
                                             (float)a.w * INV + bv.w);
        }
    }
}

// ---------------- fallback (small ws): atomic scatter ----------------
__global__ __launch_bounds__(256) void init_out_kernel(const float* __restrict__ b,
                                                       float* __restrict__ out) {
    const int i = blockIdx.x * blockDim.x + threadIdx.x;
    const int total4 = N_NODES * D / 4;
    if (i < total4) {
        const float4* b4 = reinterpret_cast<const float4*>(b);
        reinterpret_cast<float4*>(out)[i] = b4[i & 15];
    }
}

__global__ __launch_bounds__(256) void scatter_kernel(const int* __restrict__ erow,
                                                      const int* __restrict__ ecol,
                                                      const float* __restrict__ eval_,
                                                      const unsigned short* __restrict__ y,
                                                      float* __restrict__ out, int ne) {
    const int e    = blockIdx.x * 4 + (threadIdx.x >> 6);
    const int lane = threadIdx.x & 63;
    if (e >= ne) return;
    atomicAdd(&out[erow[e] * D + lane], eval_[e] * bf16_to_f32(y[ecol[e] * D + lane]));
}

extern "C" void kernel_launch(void* const* d_in, const int* in_sizes, int n_in,
                              void* d_out, int out_size, void* d_ws, size_t ws_size,
                              hipStream_t stream) {
    const float* x     = (const float*)d_in[0];
    const int*   erow  = (const int*)  d_in[1];
    const int*   ecol  = (const int*)  d_in[2];
    const float* eval_ = (const float*)d_in[3];
    const float* W     = (const float*)d_in[4];
    const float* b     = (const float*)d_in[5];
    float*       out   = (float*)d_out;
    const int ne = in_sizes[1];

    char* ws = (char*)d_ws;
    // workspace layout (aligned)
    const size_t Y_OFF     = 0;             // 12,800,000 B
    const size_t PEDGE_OFF = 12800000;      // 4,000,000 B
    const size_t H2D_OFF   = 16800000;      // npb*NBINS*4 (<= 4,000,000 B)
    const size_t SCAN_OFF  = 20800000;      // <= 4,000,000 B
    const size_t BSUM_OFF  = 24800000;      // 8,192 B
    const size_t BST_OFF   = 24808192;      // (NBINS+1)*4 = 6,256 B
    const size_t TOTAL     = 24814592;

    unsigned short* y = (unsigned short*)(ws + Y_OFF);

    const int npb      = (ne + PE - 1) / PE;       // 489 @ 1M edges
    const int totalSc  = NBINS * npb;              // 764,307
    const int nblocksA = (totalSc + 1023) / 1024;  // 747 (<= 2048 for scanB)

    if (ws_size >= TOTAL && npb <= 1341) {
        u32* pedge    = (u32*)(ws + PEDGE_OFF);
        int* hist2d   = (int*)(ws + H2D_OFF);
        int* scan2d   = (int*)(ws + SCAN_OFF);
        int* bsum     = (int*)(ws + BSUM_OFF);
        int* binStart = (int*)(ws + BST_OFF);

        // 1) per-block bin histograms
        hist_kernel<<<npb, 256, 0, stream>>>(erow, hist2d, ne);

        // 2) bin-major exclusive scan (two kernels — NO device fences, r11 post-mortem)
        scanA_kernel<<<nblocksA, 256, 0, stream>>>(hist2d, scan2d, bsum, totalSc, npb);
        scanB_kernel<<<1, 1024, 0, stream>>>(bsum, nblocksA);

        // 3) fused: partition (blocks [0,npb)) || y = bf16(x @ W^T) (blocks [npb, npb+XWB))
        xw_part_kernel<<<npb + XWB, 256, 0, stream>>>(x, W, y, erow, ecol, eval_,
                                                      scan2d, bsum, pedge, binStart, ne, npb);

        // 4) per-bin aggregation + bias
        aggregate_kernel<<<NBINS, 512, 0, stream>>>(binStart, pedge, y, b, (float4*)out);
    } else {
        xw_part_kernel<<<XWB, 256, 0, stream>>>(x, W, y, erow, ecol, eval_,
                                                (int*)ws, (int*)ws, (u32*)ws, (int*)ws, 0, 0);
        init_out_kernel<<<(N_NODES * D / 4 + 255) / 256, 256, 0, stream>>>(b, out);
        scatter_kernel<<<(ne + 3) / 4, 256, 0, stream>>>(erow, ecol, eval_, y, out, ne);
    }
}